// Round 19
// baseline (397.915 us; speedup 1.0000x reference)
//
#include <hip/hip_runtime.h>
#include <math.h>

#define QN 20000
#define PN 80000   // QN*4
#define CN 128
#define NVIEW 6

typedef __attribute__((ext_vector_type(8))) _Float16 h8;
typedef __attribute__((ext_vector_type(4))) _Float16 h4;
typedef __attribute__((ext_vector_type(4))) float f32x4;

__device__ __forceinline__ void gload16(const void* g, void* l) {
  __builtin_amdgcn_global_load_lds(
      (const __attribute__((address_space(1))) void*)g,
      (__attribute__((address_space(3))) void*)l, 16, 0, 0);
}

// ---------------- prep mega-dispatch: wtrans(6 layers) + fcvt + pe_in --------
__global__ __launch_bounds__(256) void prep_all(
    const float* __restrict__ w0, const float* __restrict__ w1,
    const float* __restrict__ w2, const float* __restrict__ w3,
    const float* __restrict__ w4, const float* __restrict__ w5,
    _Float16* __restrict__ wbase,
    const float* __restrict__ s0, const float* __restrict__ s1,
    const float* __restrict__ s2, const float* __restrict__ s3,
    _Float16* __restrict__ fdst,
    const float* __restrict__ rp, _Float16* __restrict__ pedst) {
  int b = blockIdx.x;
  if (b < 2736) {  // ---- weight transpose ----
    __shared__ float t[32][33];
    const float* W; _Float16* T; int K, N, Kp, nbx, lb;
    if (b < 16)        { W = w0; T = wbase + 0;       K = 60;   N = 256;  Kp = 64;   nbx = 8;  lb = b; }
    else if (b < 48)   { W = w1; T = wbase + 32768;   K = 256;  N = 128;  Kp = 256;  nbx = 4;  lb = b - 16; }
    else if (b < 560)  { W = w2; T = wbase + 98304;   K = 512;  N = 1024; Kp = 512;  nbx = 32; lb = b - 48; }
    else if (b < 1584) { W = w3; T = wbase + 1146880; K = 1024; N = 1024; Kp = 1024; nbx = 32; lb = b - 560; }
    else if (b < 2608) { W = w4; T = wbase + 3244032; K = 1024; N = 1024; Kp = 1024; nbx = 32; lb = b - 1584; }
    else               { W = w5; T = wbase + 5341184; K = 1024; N = 128;  Kp = 1024; nbx = 4;  lb = b - 2608; }
    const int n0 = (lb % nbx) * 32, k0 = (lb / nbx) * 32;
    const int tx = threadIdx.x & 31, ty = threadIdx.x >> 5;
    #pragma unroll
    for (int j = 0; j < 4; ++j) {
      int k = k0 + ty + j * 8;
      t[ty + j * 8][tx] = (k < K) ? W[(size_t)k * N + n0 + tx] : 0.f;
    }
    __syncthreads();
    #pragma unroll
    for (int j = 0; j < 4; ++j) {
      int n = n0 + ty + j * 8;
      int k = k0 + tx;
      T[(size_t)n * Kp + k] = (_Float16)t[tx][ty + j * 8];
    }
  } else if (b < 13956) {  // ---- feats f32 -> f16 ----
    size_t i = (size_t)(b - 2736) * 256 + threadIdx.x;  // float4 index
    const float* s; size_t off;
    if (i < 2162688)      { s = s0; off = 0; }
    else if (i < 2703360) { s = s1; off = 2162688; }
    else if (i < 2838528) { s = s2; off = 2703360; }
    else                  { s = s3; off = 2838528; }
    f32x4 v = *(const f32x4*)(s + (i - off) * 4);
    h4 o;
    o[0] = (_Float16)v[0]; o[1] = (_Float16)v[1];
    o[2] = (_Float16)v[2]; o[3] = (_Float16)v[3];
    *(h4*)(fdst + i * 4) = o;
  } else {  // ---- PE features ----
    int idx = (b - 13956) * 256 + threadIdx.x;
    int p = idx >> 6, k = idx & 63;
    float val = 0.f;
    if (k < 60) {
      int q = p >> 2, z = p & 3;
      int d = k / 20, r = k - d * 20;
      int j = (r >= 10) ? (r - 10) : r;
      float pos = rp[((size_t)z * QN + q) * 3 + d];
      float ang = pos * ((float)(1 << j) * 3.14159265358979323846f);
      val = (r >= 10) ? cosf(ang) : sinf(ang);
    }
    pedst[idx] = (_Float16)val;
  }
}

// ---------------- level-weight softmax: lw[p][4] = softmax(posE@wtw + wtb) ---
__global__ __launch_bounds__(256) void lw_kernel(const _Float16* __restrict__ posE,
                                                 const float* __restrict__ wtw,
                                                 const float* __restrict__ wtb,
                                                 float* __restrict__ lw) {
  __shared__ float swtT[512];  // transposed [4][128]
  __shared__ float sb[4];
  const int tid = threadIdx.x;
  for (int i = tid; i < 512; i += 256) swtT[(i & 3) * 128 + (i >> 2)] = wtw[i];
  if (tid < 4) sb[tid] = wtb[tid];
  __syncthreads();

  const int wave = tid >> 6, lane = tid & 63;
  const int grp = lane >> 4, s = lane & 15;
  const int p = blockIdx.x * 16 + wave * 4 + grp;
  const int c0 = s * 8;
  h8 pa = *(const h8*)(posE + (size_t)p * CN + c0);

  float lg[4];
  #pragma unroll
  for (int l = 0; l < 4; ++l) {
    const float* w = swtT + l * 128 + c0;
    float acc = 0.f;
    #pragma unroll
    for (int j = 0; j < 8; ++j) acc = fmaf((float)pa[j], w[j], acc);
    lg[l] = acc;
  }
  #pragma unroll
  for (int off = 8; off > 0; off >>= 1) {
    lg[0] += __shfl_xor(lg[0], off);
    lg[1] += __shfl_xor(lg[1], off);
    lg[2] += __shfl_xor(lg[2], off);
    lg[3] += __shfl_xor(lg[3], off);
  }
  lg[0] += sb[0]; lg[1] += sb[1]; lg[2] += sb[2]; lg[3] += sb[3];
  float mx = fmaxf(fmaxf(lg[0], lg[1]), fmaxf(lg[2], lg[3]));
  float e0 = __expf(lg[0] - mx), e1 = __expf(lg[1] - mx);
  float e2 = __expf(lg[2] - mx), e3 = __expf(lg[3] - mx);
  float esr = 1.f / (e0 + e1 + e2 + e3);
  if (s == 0) {
    f32x4 o = {e0 * esr, e1 * esr, e2 * esr, e3 * esr};
    *(f32x4*)(lw + (size_t)p * 4) = o;
  }
}

// ---------------- fp16 MFMA GEMM (ROUND-10 PROVEN CONFIG) --------------------
// 128x128, BK=32, 2x2 waves, 4 blocks/CU, 2-phase, one __syncthreads/tile.
template <bool RELU, int OUT>
__global__ __launch_bounds__(256, 4) void gemm_h(const _Float16* __restrict__ A,
                                                 const _Float16* __restrict__ B,
                                                 const float* __restrict__ bias,
                                                 float* __restrict__ Cf,
                                                 _Float16* __restrict__ Ch,
                                                 int M, int N, int K,
                                                 int nbn) {
  __shared__ _Float16 sm[2][2][4096];  // [buf][A,B][128 rows * 32 k]
  const int tid = threadIdx.x;
  const int wave = tid >> 6, lane = tid & 63;
  const int wr = wave >> 1, wc = wave & 1;
  const int g = lane >> 4, r16 = lane & 15;

  const int nwg = gridDim.x;
  const int q8 = nwg >> 3, r8 = nwg & 7;
  const int xcd = blockIdx.x & 7, sub = blockIdx.x >> 3;
  const int wg = (xcd < r8 ? xcd * (q8 + 1) : r8 * (q8 + 1) + (xcd - r8) * q8) + sub;
  const int bn = (wg % nbn) * 128;
  const int bm = (wg / nbn) * 128;
  const int nt = K >> 5;

  f32x4 acc[4][4];
  #pragma unroll
  for (int i = 0; i < 4; ++i)
    #pragma unroll
    for (int j = 0; j < 4; ++j) acc[i][j] = {0.f, 0.f, 0.f, 0.f};

  auto STAGE = [&](int buf, int t) {
    const int kof = t << 5;
    const int rsub = lane >> 2;
    const int slot0 = lane & 3;
    #pragma unroll
    for (int pl = 0; pl < 2; ++pl) {
      const _Float16* P = (pl == 0) ? A : B;
      const int rbase = (pl == 0) ? bm : bn;
      #pragma unroll
      for (int i = 0; i < 2; ++i) {
        int group = wave * 2 + i;
        int row = group * 16 + rsub;
        int slot = slot0 ^ ((row >> 1) & 3);
        int gr = rbase + row;
        if (pl == 0 && gr >= M) gr = M - 1;
        gload16(P + (size_t)gr * K + kof + slot * 8,
                &sm[buf][pl][group * 512]);
      }
    }
  };

  auto COMPUTE = [&](int buf) {
    h8 a[4], b[4];
    #pragma unroll
    for (int mi = 0; mi < 4; ++mi) {
      int row = wr * 64 + mi * 16 + r16;
      int off = row * 32 + ((g ^ ((row >> 1) & 3)) * 8);
      a[mi] = *(const h8*)&sm[buf][0][off];
    }
    #pragma unroll
    for (int ni = 0; ni < 4; ++ni) {
      int row = wc * 64 + ni * 16 + r16;
      int off = row * 32 + ((g ^ ((row >> 1) & 3)) * 8);
      b[ni] = *(const h8*)&sm[buf][1][off];
    }
    #pragma unroll
    for (int mi = 0; mi < 4; ++mi)
      #pragma unroll
      for (int ni = 0; ni < 4; ++ni)
        acc[mi][ni] = __builtin_amdgcn_mfma_f32_16x16x32_f16(a[mi], b[ni], acc[mi][ni], 0, 0, 0);
  };

  STAGE(0, 0);
  __syncthreads();

  for (int t = 0; t < nt; ++t) {
    if (t + 1 < nt) STAGE((t + 1) & 1, t + 1);
    COMPUTE(t & 1);
    __syncthreads();
  }

  #pragma unroll
  for (int mi = 0; mi < 4; ++mi) {
    int gr0 = bm + wr * 64 + mi * 16 + (lane >> 4) * 4;
    #pragma unroll
    for (int ni = 0; ni < 4; ++ni) {
      int gc = bn + wc * 64 + ni * 16 + r16;
      float bv = bias[gc];
      #pragma unroll
      for (int r = 0; r < 4; ++r) {
        int row = gr0 + r;
        if (row >= M) continue;
        float v = acc[mi][ni][r] + bv;
        if (RELU) v = fmaxf(v, 0.f);
        if (OUT == 0) Cf[(size_t)row * N + gc] = v;
        else          Ch[(size_t)row * N + gc] = (_Float16)v;
      }
    }
  }
}

// ---------------- 128x256-tile GEMM with counted-vmcnt pipeline --------------
// Composition of two individually-verified pieces: r11's 128x256 geometry
// (bit-exact numerics, failed only on occupancy under full-drain) + r9's
// fenced counted-vmcnt protocol (bit-exact numerics, neutral at 128^2 where
// TLP already hid the drain). Wave tile 128x64 (acc[8][4]) cuts LDS bytes/MFMA
// 25%; vmcnt(6) = per-wave loads of one tile (A:2 + B:4) keeps tile t+1 in
// flight across barriers so 2 blocks/CU suffices. N % 256 == 0.
template <bool RELU, int OUT>
__global__ __launch_bounds__(256, 2) void gemm_h256(const _Float16* __restrict__ A,
                                                    const _Float16* __restrict__ B,
                                                    const float* __restrict__ bias,
                                                    float* __restrict__ Cf,
                                                    _Float16* __restrict__ Ch,
                                                    int M, int N, int K,
                                                    int nbn) {
  __shared__ _Float16 smA[2][128 * 32];  // 8 KB per buf
  __shared__ _Float16 smB[2][256 * 32];  // 16 KB per buf
  const int tid = threadIdx.x;
  const int wave = tid >> 6, lane = tid & 63;
  const int wc = wave;                   // 4 waves across N
  const int g = lane >> 4, r16 = lane & 15;

  const int nwg = gridDim.x;
  const int q8 = nwg >> 3, r8 = nwg & 7;
  const int xcd = blockIdx.x & 7, sub = blockIdx.x >> 3;
  const int wg = (xcd < r8 ? xcd * (q8 + 1) : r8 * (q8 + 1) + (xcd - r8) * q8) + sub;
  const int bn = (wg % nbn) * 256;
  const int bm = (wg / nbn) * 128;
  const int nt = K >> 5;

  f32x4 acc[8][4];
  #pragma unroll
  for (int i = 0; i < 8; ++i)
    #pragma unroll
    for (int j = 0; j < 4; ++j) acc[i][j] = {0.f, 0.f, 0.f, 0.f};

  // per wave: A 2 instr + B 4 instr = 6 vmem ops per tile
  auto STAGE = [&](int buf, int t) {
    const int kof = t << 5;
    const int rsub = lane >> 2;
    const int slot0 = lane & 3;
    #pragma unroll
    for (int i = 0; i < 2; ++i) {          // A: 128 rows, 8 groups, 2/wave
      int group = wave * 2 + i;
      int row = group * 16 + rsub;
      int slot = slot0 ^ ((row >> 1) & 3);
      int gr = bm + row; if (gr >= M) gr = M - 1;
      gload16(A + (size_t)gr * K + kof + slot * 8, &smA[buf][group * 512]);
    }
    #pragma unroll
    for (int i = 0; i < 4; ++i) {          // B: 256 rows, 16 groups, 4/wave
      int group = wave * 4 + i;
      int row = group * 16 + rsub;
      int slot = slot0 ^ ((row >> 1) & 3);
      gload16(B + (size_t)(bn + row) * K + kof + slot * 8, &smB[buf][group * 512]);
    }
  };

  auto COMPUTE = [&](int buf) {
    h8 b[4];
    #pragma unroll
    for (int ni = 0; ni < 4; ++ni) {
      int row = wc * 64 + ni * 16 + r16;
      int off = row * 32 + ((g ^ ((row >> 1) & 3)) * 8);
      b[ni] = *(const h8*)&smB[buf][off];
    }
    #pragma unroll
    for (int mi = 0; mi < 8; ++mi) {
      int row = mi * 16 + r16;
      int off = row * 32 + ((g ^ ((row >> 1) & 3)) * 8);
      h8 a = *(const h8*)&smA[buf][off];
      #pragma unroll
      for (int ni = 0; ni < 4; ++ni)
        acc[mi][ni] = __builtin_amdgcn_mfma_f32_16x16x32_f16(a, b[ni], acc[mi][ni], 0, 0, 0);
    }
  };

  STAGE(0, 0);
  asm volatile("" ::: "memory");  // pin issue order vs loop's first STAGE

  for (int t = 0; t < nt; ++t) {
    const int cur = t & 1;
    if (t + 1 < nt) {
      STAGE(cur ^ 1, t + 1);
      asm volatile("" ::: "memory");
      // retire tile t's 6 loads (oldest); tile t+1's 6 stay in flight
      asm volatile("s_waitcnt vmcnt(6)\n\ts_barrier" ::: "memory");
    } else {
      asm volatile("s_waitcnt vmcnt(0)\n\ts_barrier" ::: "memory");
    }
    COMPUTE(cur);
    // WAR fence: my LDS reads done, then all-waves barrier (no vmem drain)
    asm volatile("s_waitcnt lgkmcnt(0)\n\ts_barrier" ::: "memory");
  }

  #pragma unroll
  for (int mi = 0; mi < 8; ++mi) {
    int gr0 = bm + mi * 16 + (lane >> 4) * 4;
    #pragma unroll
    for (int ni = 0; ni < 4; ++ni) {
      int gc = bn + wc * 64 + ni * 16 + r16;
      float bv = bias[gc];
      #pragma unroll
      for (int r = 0; r < 4; ++r) {
        int row = gr0 + r;
        if (row >= M) continue;
        float v = acc[mi][ni][r] + bv;
        if (RELU) v = fmaxf(v, 0.f);
        if (OUT == 0) Cf[(size_t)row * N + gc] = v;
        else          Ch[(size_t)row * N + gc] = (_Float16)v;
      }
    }
  }
}

// ---------------- fused projection + bilinear sample -------------------------
// 2 pts/wave + interior fast path + f16 feats + precomputed lw (r18: 66.9us)
__global__ __launch_bounds__(256) void sample_kernel(
    const _Float16* __restrict__ fbase,
    const float* __restrict__ rp, const float* __restrict__ l2i,
    const float* __restrict__ lw,
    const _Float16* __restrict__ posE, _Float16* __restrict__ X0) {
  __shared__ float sl2i[96];
  const int tid = threadIdx.x;
  if (tid < 96) sl2i[tid] = l2i[tid];
  __syncthreads();

  const _Float16* FL[4] = {fbase, fbase + 8650752, fbase + 10813440,
                           fbase + 11354112};

  const int wave = tid >> 6, lane = tid & 63;
  const int half = lane >> 5, s = lane & 31;
  const int p = blockIdx.x * 8 + wave * 2 + half;
  const int q = p >> 2, z = p & 3;

  const float X  = rp[((size_t)z * QN + q) * 3 + 0] * 100.f - 50.f;
  const float Y  = rp[((size_t)z * QN + q) * 3 + 1] * 100.f - 50.f;
  const float Zc = rp[((size_t)z * QN + q) * 3 + 2] * 8.f - 4.f;

  const int c0 = s * 4;
  h4 pa = *(const h4*)(posE + (size_t)p * CN + c0);
  const float pe0 = (float)pa[0], pe1 = (float)pa[1];
  const float pe2 = (float)pa[2], pe3 = (float)pa[3];

  f32x4 lw4 = *(const f32x4*)(lw + (size_t)p * 4);
  float swl[4] = {lw4[0], lw4[1], lw4[2], lw4[3]};

  float a0 = 0.f, a1 = 0.f, a2 = 0.f, a3 = 0.f;
  for (int n = 0; n < NVIEW; n++) {
    const float* Mx = sl2i + n * 16;
    float cam0 = Mx[0] * X + Mx[1] * Y + Mx[2]  * Zc + Mx[3];
    float cam1 = Mx[4] * X + Mx[5] * Y + Mx[6]  * Zc + Mx[7];
    float cam2 = Mx[8] * X + Mx[9] * Y + Mx[10] * Zc + Mx[11];
    float denom = fmaxf(cam2, 1e-5f);
    float u = cam0 / denom * (1.f / 704.f);
    float v = cam1 / denom * (1.f / 256.f);
    bool valid = (cam2 > 1e-5f) & (u > 0.f) & (u < 1.f) & (v > 0.f) & (v < 1.f);
    if (!valid) continue;
    float px3 = u * 22.f - 0.5f, py3 = v * 8.f - 0.5f;
    bool interior = (px3 >= 0.f) & (py3 >= 0.f) & (px3 < 21.f) & (py3 < 7.f);
    if (interior) {
      #pragma unroll
      for (int l = 0; l < 4; l++) {
        const int Hl = 64 >> l, Wl = 176 >> l;
        float pxl = u * (float)Wl - 0.5f;
        float pyl = v * (float)Hl - 0.5f;
        float fx = floorf(pxl), fy = floorf(pyl);
        int x0 = (int)fx, y0 = (int)fy;
        float wx = pxl - fx, wy = pyl - fy;
        float w1r = wy * swl[l], w0r = swl[l] - w1r;
        float w01 = w0r * wx, w00 = w0r - w01;
        float w11 = w1r * wx, w10 = w1r - w11;
        const _Float16* cp = FL[l]
            + ((size_t)n * (Hl * Wl) + (size_t)(y0 * Wl + x0)) * CN + c0;
        h4 v00 = *(const h4*)(cp);
        h4 v01 = *(const h4*)(cp + CN);
        h4 v10 = *(const h4*)(cp + Wl * CN);
        h4 v11 = *(const h4*)(cp + Wl * CN + CN);
        a0 = fmaf(w00, (float)v00[0], fmaf(w01, (float)v01[0], fmaf(w10, (float)v10[0], fmaf(w11, (float)v11[0], a0))));
        a1 = fmaf(w00, (float)v00[1], fmaf(w01, (float)v01[1], fmaf(w10, (float)v10[1], fmaf(w11, (float)v11[1], a1))));
        a2 = fmaf(w00, (float)v00[2], fmaf(w01, (float)v01[2], fmaf(w10, (float)v10[2], fmaf(w11, (float)v11[2], a2))));
        a3 = fmaf(w00, (float)v00[3], fmaf(w01, (float)v01[3], fmaf(w10, (float)v10[3], fmaf(w11, (float)v11[3], a3))));
      }
    } else {
      #pragma unroll
      for (int l = 0; l < 4; l++) {
        const int Hl = 64 >> l, Wl = 176 >> l;
        float pxl = u * (float)Wl - 0.5f;
        float pyl = v * (float)Hl - 0.5f;
        float fx = floorf(pxl), fy = floorf(pyl);
        int x0 = (int)fx, y0 = (int)fy;
        float wx = pxl - fx, wy = pyl - fy;
        float w1r = wy * swl[l], w0r = swl[l] - w1r;
        const float wxs[2] = {1.f - wx, wx};
        const float wrs[2] = {w0r, w1r};
        const _Float16* fb = FL[l] + (size_t)n * (Hl * Wl) * CN;
        #pragma unroll
        for (int cy = 0; cy < 2; cy++) {
          #pragma unroll
          for (int cx = 0; cx < 2; cx++) {
            int xi = x0 + cx, yi = y0 + cy;
            bool inb = ((unsigned)xi < (unsigned)Wl) & ((unsigned)yi < (unsigned)Hl);
            int off = inb ? (yi * Wl + xi) * CN : 0;
            float wgt = inb ? (wrs[cy] * wxs[cx]) : 0.f;
            h4 vv = *(const h4*)(fb + off + c0);
            a0 = fmaf(wgt, (float)vv[0], a0);
            a1 = fmaf(wgt, (float)vv[1], a1);
            a2 = fmaf(wgt, (float)vv[2], a2);
            a3 = fmaf(wgt, (float)vv[3], a3);
          }
        }
      }
    }
  }
  h4 o;
  o[0] = (_Float16)(a0 + pe0);
  o[1] = (_Float16)(a1 + pe1);
  o[2] = (_Float16)(a2 + pe2);
  o[3] = (_Float16)(a3 + pe3);
  *(h4*)&X0[(size_t)p * CN + c0] = o;
}

extern "C" void kernel_launch(void* const* d_in, const int* in_sizes, int n_in,
                              void* d_out, int out_size, void* d_ws, size_t ws_size,
                              hipStream_t stream) {
  const float* feat0 = (const float*)d_in[0];
  const float* feat1 = (const float*)d_in[1];
  const float* feat2 = (const float*)d_in[2];
  const float* feat3 = (const float*)d_in[3];
  const float* rp    = (const float*)d_in[4];
  const float* l2i   = (const float*)d_in[5];
  const float* pe_w1 = (const float*)d_in[6];
  const float* pe_b1 = (const float*)d_in[7];
  const float* pe_w2 = (const float*)d_in[8];
  const float* pe_b2 = (const float*)d_in[9];
  const float* wt_w  = (const float*)d_in[10];
  const float* wt_b  = (const float*)d_in[11];
  const float* hm_w1 = (const float*)d_in[12];
  const float* hm_b1 = (const float*)d_in[13];
  const float* hm_w2 = (const float*)d_in[14];
  const float* hm_b2 = (const float*)d_in[15];
  const float* hm_w3 = (const float*)d_in[16];
  const float* hm_b3 = (const float*)d_in[17];
  const float* hm_w4 = (const float*)d_in[18];
  const float* hm_b4 = (const float*)d_in[19];
  float* out = (float*)d_out;

  char* ws = (char*)d_ws;
  typedef _Float16 h16;
  h16* wPE1 = (h16*)(ws + 0);         // 256x64
  h16* wPE2 = (h16*)(ws + 65536);     // 128x256
  h16* wH1  = (h16*)(ws + 196608);    // 1024x512
  h16* wH2  = (h16*)(ws + 2293760);   // 1024x1024
  h16* wH3  = (h16*)(ws + 6488064);   // 1024x1024
  h16* wH4  = (h16*)(ws + 10682368);  // 128x1024

  h16*   posE = (h16*)(ws + 11534336);   // [80000][128] f16
  float* lwga = (float*)(ws + 33000000); // [80000][4] f32 level weights
  h16*   hpe  = (h16*)(ws + 53000192);   // [80000][256] f16
  h16*   pein = (h16*)(ws + 94000128);   // [80000][64] f16
  h16*   X0   = (h16*)(ws + 53000192);   // [20000][512] f16 (hpe dead)
  h16*   H1   = (h16*)(ws + 94000128);   // [20000][1024] f16 (pein dead)
  h16*   H2   = (h16*)(ws + 11534336);   // (posE dead after sample)
  h16*   H3   = (h16*)(ws + 94000128);   // (H1 dead)
  h16*   f16b = (h16*)(ws + 136000000);  // feats f16, 22.98 MB

  // 0. single prep dispatch
  prep_all<<<33956, 256, 0, stream>>>(pe_w1, pe_w2, hm_w1, hm_w2, hm_w3, hm_w4,
                                      (h16*)ws, feat0, feat1, feat2, feat3,
                                      f16b, rp, pein);

  // 1. PE MLP: 64 -> 256 (relu) -> 128 (f16 posE)
  gemm_h<true, 1><<<2 * 625, 256, 0, stream>>>(pein, wPE1, pe_b1, nullptr, hpe, PN, 256, 64, 2);
  gemm_h<false, 1><<<1 * 625, 256, 0, stream>>>(hpe, wPE2, pe_b2, nullptr, posE, PN, 128, 256, 1);

  // 2. level-weight softmax
  lw_kernel<<<PN / 16, 256, 0, stream>>>(posE, wt_w, wt_b, lwga);

  // 3. fused projection + sampling -> X0 f16
  sample_kernel<<<PN / 8, 256, 0, stream>>>(f16b, rp, l2i, lwga, posE, X0);

  // 4. head MLP: H1-H3 on 128x256 counted-vmcnt tiles; H4 (N=128) on gemm_h
  gemm_h256<true, 1><<<4 * 157, 256, 0, stream>>>(X0, wH1, hm_b1, nullptr, H1, QN, 1024, 512, 4);
  gemm_h256<true, 1><<<4 * 157, 256, 0, stream>>>(H1, wH2, hm_b2, nullptr, H2, QN, 1024, 1024, 4);
  gemm_h256<true, 1><<<4 * 157, 256, 0, stream>>>(H2, wH3, hm_b3, nullptr, H3, QN, 1024, 1024, 4);
  gemm_h<false, 0><<<1 * 157, 256, 0, stream>>>(H3, wH4, hm_b4, out, nullptr, QN, 128, 1024, 1);
}

// Round 20
// 306.089 us; speedup vs baseline: 1.3000x; 1.3000x over previous
//
#include <hip/hip_runtime.h>
#include <math.h>

#define QN 20000
#define PN 80000   // QN*4
#define CN 128
#define NVIEW 6

typedef __attribute__((ext_vector_type(8))) _Float16 h8;
typedef __attribute__((ext_vector_type(4))) _Float16 h4;
typedef __attribute__((ext_vector_type(4))) float f32x4;

__device__ __forceinline__ void gload16(const void* g, void* l) {
  __builtin_amdgcn_global_load_lds(
      (const __attribute__((address_space(1))) void*)g,
      (__attribute__((address_space(3))) void*)l, 16, 0, 0);
}

// ---------------- prep mega-dispatch: wtrans(6 layers) + fcvt + pe_in --------
__global__ __launch_bounds__(256) void prep_all(
    const float* __restrict__ w0, const float* __restrict__ w1,
    const float* __restrict__ w2, const float* __restrict__ w3,
    const float* __restrict__ w4, const float* __restrict__ w5,
    _Float16* __restrict__ wbase,
    const float* __restrict__ s0, const float* __restrict__ s1,
    const float* __restrict__ s2, const float* __restrict__ s3,
    _Float16* __restrict__ fdst,
    const float* __restrict__ rp, _Float16* __restrict__ pedst) {
  int b = blockIdx.x;
  if (b < 2736) {  // ---- weight transpose ----
    __shared__ float t[32][33];
    const float* W; _Float16* T; int K, N, Kp, nbx, lb;
    if (b < 16)        { W = w0; T = wbase + 0;       K = 60;   N = 256;  Kp = 64;   nbx = 8;  lb = b; }
    else if (b < 48)   { W = w1; T = wbase + 32768;   K = 256;  N = 128;  Kp = 256;  nbx = 4;  lb = b - 16; }
    else if (b < 560)  { W = w2; T = wbase + 98304;   K = 512;  N = 1024; Kp = 512;  nbx = 32; lb = b - 48; }
    else if (b < 1584) { W = w3; T = wbase + 1146880; K = 1024; N = 1024; Kp = 1024; nbx = 32; lb = b - 560; }
    else if (b < 2608) { W = w4; T = wbase + 3244032; K = 1024; N = 1024; Kp = 1024; nbx = 32; lb = b - 1584; }
    else               { W = w5; T = wbase + 5341184; K = 1024; N = 128;  Kp = 1024; nbx = 4;  lb = b - 2608; }
    const int n0 = (lb % nbx) * 32, k0 = (lb / nbx) * 32;
    const int tx = threadIdx.x & 31, ty = threadIdx.x >> 5;
    #pragma unroll
    for (int j = 0; j < 4; ++j) {
      int k = k0 + ty + j * 8;
      t[ty + j * 8][tx] = (k < K) ? W[(size_t)k * N + n0 + tx] : 0.f;
    }
    __syncthreads();
    #pragma unroll
    for (int j = 0; j < 4; ++j) {
      int n = n0 + ty + j * 8;
      int k = k0 + tx;
      T[(size_t)n * Kp + k] = (_Float16)t[tx][ty + j * 8];
    }
  } else if (b < 13956) {  // ---- feats f32 -> f16 ----
    size_t i = (size_t)(b - 2736) * 256 + threadIdx.x;  // float4 index
    const float* s; size_t off;
    if (i < 2162688)      { s = s0; off = 0; }
    else if (i < 2703360) { s = s1; off = 2162688; }
    else if (i < 2838528) { s = s2; off = 2703360; }
    else                  { s = s3; off = 2838528; }
    f32x4 v = *(const f32x4*)(s + (i - off) * 4);
    h4 o;
    o[0] = (_Float16)v[0]; o[1] = (_Float16)v[1];
    o[2] = (_Float16)v[2]; o[3] = (_Float16)v[3];
    *(h4*)(fdst + i * 4) = o;
  } else {  // ---- PE features ----
    int idx = (b - 13956) * 256 + threadIdx.x;
    int p = idx >> 6, k = idx & 63;
    float val = 0.f;
    if (k < 60) {
      int q = p >> 2, z = p & 3;
      int d = k / 20, r = k - d * 20;
      int j = (r >= 10) ? (r - 10) : r;
      float pos = rp[((size_t)z * QN + q) * 3 + d];
      float ang = pos * ((float)(1 << j) * 3.14159265358979323846f);
      val = (r >= 10) ? cosf(ang) : sinf(ang);
    }
    pedst[idx] = (_Float16)val;
  }
}

// ---------------- level-weight softmax: lw[p][4] = softmax(posE@wtw + wtb) ---
__global__ __launch_bounds__(256) void lw_kernel(const _Float16* __restrict__ posE,
                                                 const float* __restrict__ wtw,
                                                 const float* __restrict__ wtb,
                                                 float* __restrict__ lw) {
  __shared__ float swtT[512];  // transposed [4][128]
  __shared__ float sb[4];
  const int tid = threadIdx.x;
  for (int i = tid; i < 512; i += 256) swtT[(i & 3) * 128 + (i >> 2)] = wtw[i];
  if (tid < 4) sb[tid] = wtb[tid];
  __syncthreads();

  const int wave = tid >> 6, lane = tid & 63;
  const int grp = lane >> 4, s = lane & 15;
  const int p = blockIdx.x * 16 + wave * 4 + grp;
  const int c0 = s * 8;
  h8 pa = *(const h8*)(posE + (size_t)p * CN + c0);

  float lg[4];
  #pragma unroll
  for (int l = 0; l < 4; ++l) {
    const float* w = swtT + l * 128 + c0;
    float acc = 0.f;
    #pragma unroll
    for (int j = 0; j < 8; ++j) acc = fmaf((float)pa[j], w[j], acc);
    lg[l] = acc;
  }
  #pragma unroll
  for (int off = 8; off > 0; off >>= 1) {
    lg[0] += __shfl_xor(lg[0], off);
    lg[1] += __shfl_xor(lg[1], off);
    lg[2] += __shfl_xor(lg[2], off);
    lg[3] += __shfl_xor(lg[3], off);
  }
  lg[0] += sb[0]; lg[1] += sb[1]; lg[2] += sb[2]; lg[3] += sb[3];
  float mx = fmaxf(fmaxf(lg[0], lg[1]), fmaxf(lg[2], lg[3]));
  float e0 = __expf(lg[0] - mx), e1 = __expf(lg[1] - mx);
  float e2 = __expf(lg[2] - mx), e3 = __expf(lg[3] - mx);
  float esr = 1.f / (e0 + e1 + e2 + e3);
  if (s == 0) {
    f32x4 o = {e0 * esr, e1 * esr, e2 * esr, e3 * esr};
    *(f32x4*)(lw + (size_t)p * 4) = o;
  }
}

// ---------------- fp16 MFMA GEMM (ROUND-10 PROVEN CONFIG) --------------------
// 128x128, BK=32, 2x2 waves, 4 blocks/CU, 2-phase, one __syncthreads/tile.
// Used for PE1/PE2/H4 (small-K / N=128 layers).
template <bool RELU, int OUT>
__global__ __launch_bounds__(256, 4) void gemm_h(const _Float16* __restrict__ A,
                                                 const _Float16* __restrict__ B,
                                                 const float* __restrict__ bias,
                                                 float* __restrict__ Cf,
                                                 _Float16* __restrict__ Ch,
                                                 int M, int N, int K,
                                                 int nbn) {
  __shared__ _Float16 sm[2][2][4096];  // [buf][A,B][128 rows * 32 k]
  const int tid = threadIdx.x;
  const int wave = tid >> 6, lane = tid & 63;
  const int wr = wave >> 1, wc = wave & 1;
  const int g = lane >> 4, r16 = lane & 15;

  const int nwg = gridDim.x;
  const int q8 = nwg >> 3, r8 = nwg & 7;
  const int xcd = blockIdx.x & 7, sub = blockIdx.x >> 3;
  const int wg = (xcd < r8 ? xcd * (q8 + 1) : r8 * (q8 + 1) + (xcd - r8) * q8) + sub;
  const int bn = (wg % nbn) * 128;
  const int bm = (wg / nbn) * 128;
  const int nt = K >> 5;

  f32x4 acc[4][4];
  #pragma unroll
  for (int i = 0; i < 4; ++i)
    #pragma unroll
    for (int j = 0; j < 4; ++j) acc[i][j] = {0.f, 0.f, 0.f, 0.f};

  auto STAGE = [&](int buf, int t) {
    const int kof = t << 5;
    const int rsub = lane >> 2;
    const int slot0 = lane & 3;
    #pragma unroll
    for (int pl = 0; pl < 2; ++pl) {
      const _Float16* P = (pl == 0) ? A : B;
      const int rbase = (pl == 0) ? bm : bn;
      #pragma unroll
      for (int i = 0; i < 2; ++i) {
        int group = wave * 2 + i;
        int row = group * 16 + rsub;
        int slot = slot0 ^ ((row >> 1) & 3);
        int gr = rbase + row;
        if (pl == 0 && gr >= M) gr = M - 1;
        gload16(P + (size_t)gr * K + kof + slot * 8,
                &sm[buf][pl][group * 512]);
      }
    }
  };

  auto COMPUTE = [&](int buf) {
    h8 a[4], b[4];
    #pragma unroll
    for (int mi = 0; mi < 4; ++mi) {
      int row = wr * 64 + mi * 16 + r16;
      int off = row * 32 + ((g ^ ((row >> 1) & 3)) * 8);
      a[mi] = *(const h8*)&sm[buf][0][off];
    }
    #pragma unroll
    for (int ni = 0; ni < 4; ++ni) {
      int row = wc * 64 + ni * 16 + r16;
      int off = row * 32 + ((g ^ ((row >> 1) & 3)) * 8);
      b[ni] = *(const h8*)&sm[buf][1][off];
    }
    #pragma unroll
    for (int mi = 0; mi < 4; ++mi)
      #pragma unroll
      for (int ni = 0; ni < 4; ++ni)
        acc[mi][ni] = __builtin_amdgcn_mfma_f32_16x16x32_f16(a[mi], b[ni], acc[mi][ni], 0, 0, 0);
  };

  STAGE(0, 0);
  __syncthreads();

  for (int t = 0; t < nt; ++t) {
    if (t + 1 < nt) STAGE((t + 1) & 1, t + 1);
    COMPUTE(t & 1);
    __syncthreads();
  }

  #pragma unroll
  for (int mi = 0; mi < 4; ++mi) {
    int gr0 = bm + wr * 64 + mi * 16 + (lane >> 4) * 4;
    #pragma unroll
    for (int ni = 0; ni < 4; ++ni) {
      int gc = bn + wc * 64 + ni * 16 + r16;
      float bv = bias[gc];
      #pragma unroll
      for (int r = 0; r < 4; ++r) {
        int row = gr0 + r;
        if (row >= M) continue;
        float v = acc[mi][ni][r] + bv;
        if (RELU) v = fmaxf(v, 0.f);
        if (OUT == 0) Cf[(size_t)row * N + gc] = v;
        else          Ch[(size_t)row * N + gc] = (_Float16)v;
      }
    }
  }
}

// ---------------- m97-structure GEMM: 128x128, BK=64, SINGLE-buffered --------
// The guide's measured-874TF structure (m97/m103: 37% MfmaUtil on this chip)
// cloned in fp16. Per tile: STAGE -> __syncthreads (drain) -> 32 MFMA/wave ->
// __syncthreads (WAR). Half the drains per unit K vs BK=32; staging latency
// hidden by TLP (32KB LDS -> 4 blocks/CU, m114 implicit overlap). Swizzle for
// 128B rows: 8 slots, slot ^= row&7 involution (source & read); 8-lane read
// groups cover all 32 banks, 2-way residual = free (m136). K-ascending MFMA
// order identical to gemm_h -> bit-identical accumulation. K % 64 == 0.
template <bool RELU, int OUT>
__global__ __launch_bounds__(256, 4) void gemm97(const _Float16* __restrict__ A,
                                                 const _Float16* __restrict__ B,
                                                 const float* __restrict__ bias,
                                                 float* __restrict__ Cf,
                                                 _Float16* __restrict__ Ch,
                                                 int M, int N, int K,
                                                 int nbn) {
  __shared__ _Float16 smA[128 * 64];  // 16 KB
  __shared__ _Float16 smB[128 * 64];  // 16 KB
  const int tid = threadIdx.x;
  const int wave = tid >> 6, lane = tid & 63;
  const int wr = wave >> 1, wc = wave & 1;
  const int g = lane >> 4, r16 = lane & 15;

  const int nwg = gridDim.x;
  const int q8 = nwg >> 3, r8 = nwg & 7;
  const int xcd = blockIdx.x & 7, sub = blockIdx.x >> 3;
  const int wg = (xcd < r8 ? xcd * (q8 + 1) : r8 * (q8 + 1) + (xcd - r8) * q8) + sub;
  const int bn = (wg % nbn) * 128;
  const int bm = (wg / nbn) * 128;
  const int nt = K >> 6;  // K/64 tiles

  f32x4 acc[4][4];
  #pragma unroll
  for (int i = 0; i < 4; ++i)
    #pragma unroll
    for (int j = 0; j < 4; ++j) acc[i][j] = {0.f, 0.f, 0.f, 0.f};

  // stage one K-tile: 2 planes x 128 rows x 64 halves (16 KB/plane),
  // 16 instrs/plane, 4 per wave per plane. Rows per instr: 8 (128B each).
  auto STAGE = [&](int t) {
    const int kof = t << 6;
    const int rsub = lane >> 3;                    // 0..7 row within group
    const int slot0 = lane & 7;                    // 16B slot within row
    #pragma unroll
    for (int pl = 0; pl < 2; ++pl) {
      const _Float16* P = (pl == 0) ? A : B;
      _Float16* S = (pl == 0) ? smA : smB;
      const int rbase = (pl == 0) ? bm : bn;
      #pragma unroll
      for (int i = 0; i < 4; ++i) {
        int group = wave * 4 + i;                  // 0..15 (8 rows each)
        int row = group * 8 + rsub;                // 0..127
        int slot = slot0 ^ (row & 7);              // pre-swizzled source
        int gr = rbase + row;
        if (pl == 0 && gr >= M) gr = M - 1;
        gload16(P + (size_t)gr * K + kof + slot * 8,
                &S[group * 512]);                  // linear LDS dest
      }
    }
  };

  auto COMPUTE = [&]() {
    #pragma unroll
    for (int kk = 0; kk < 2; ++kk) {
      h8 a[4], b[4];
      #pragma unroll
      for (int mi = 0; mi < 4; ++mi) {
        int row = wr * 64 + mi * 16 + r16;
        int off = row * 64 + (((kk * 4 + g) ^ (row & 7)) * 8);  // swizzled
        a[mi] = *(const h8*)&smA[off];
      }
      #pragma unroll
      for (int ni = 0; ni < 4; ++ni) {
        int row = wc * 64 + ni * 16 + r16;
        int off = row * 64 + (((kk * 4 + g) ^ (row & 7)) * 8);
        b[ni] = *(const h8*)&smB[off];
      }
      #pragma unroll
      for (int mi = 0; mi < 4; ++mi)
        #pragma unroll
        for (int ni = 0; ni < 4; ++ni)
          acc[mi][ni] = __builtin_amdgcn_mfma_f32_16x16x32_f16(a[mi], b[ni], acc[mi][ni], 0, 0, 0);
    }
  };

  for (int t = 0; t < nt; ++t) {
    STAGE(t);
    __syncthreads();   // drain: tile t landed
    COMPUTE();
    __syncthreads();   // WAR: all reads done before next STAGE overwrites
  }

  #pragma unroll
  for (int mi = 0; mi < 4; ++mi) {
    int gr0 = bm + wr * 64 + mi * 16 + (lane >> 4) * 4;
    #pragma unroll
    for (int ni = 0; ni < 4; ++ni) {
      int gc = bn + wc * 64 + ni * 16 + r16;
      float bv = bias[gc];
      #pragma unroll
      for (int r = 0; r < 4; ++r) {
        int row = gr0 + r;
        if (row >= M) continue;
        float v = acc[mi][ni][r] + bv;
        if (RELU) v = fmaxf(v, 0.f);
        if (OUT == 0) Cf[(size_t)row * N + gc] = v;
        else          Ch[(size_t)row * N + gc] = (_Float16)v;
      }
    }
  }
}

// ---------------- fused projection + bilinear sample -------------------------
// 2 pts/wave + interior fast path + f16 feats + precomputed lw (r18: 66.9us)
__global__ __launch_bounds__(256) void sample_kernel(
    const _Float16* __restrict__ fbase,
    const float* __restrict__ rp, const float* __restrict__ l2i,
    const float* __restrict__ lw,
    const _Float16* __restrict__ posE, _Float16* __restrict__ X0) {
  __shared__ float sl2i[96];
  const int tid = threadIdx.x;
  if (tid < 96) sl2i[tid] = l2i[tid];
  __syncthreads();

  const _Float16* FL[4] = {fbase, fbase + 8650752, fbase + 10813440,
                           fbase + 11354112};

  const int wave = tid >> 6, lane = tid & 63;
  const int half = lane >> 5, s = lane & 31;
  const int p = blockIdx.x * 8 + wave * 2 + half;
  const int q = p >> 2, z = p & 3;

  const float X  = rp[((size_t)z * QN + q) * 3 + 0] * 100.f - 50.f;
  const float Y  = rp[((size_t)z * QN + q) * 3 + 1] * 100.f - 50.f;
  const float Zc = rp[((size_t)z * QN + q) * 3 + 2] * 8.f - 4.f;

  const int c0 = s * 4;
  h4 pa = *(const h4*)(posE + (size_t)p * CN + c0);
  const float pe0 = (float)pa[0], pe1 = (float)pa[1];
  const float pe2 = (float)pa[2], pe3 = (float)pa[3];

  f32x4 lw4 = *(const f32x4*)(lw + (size_t)p * 4);
  float swl[4] = {lw4[0], lw4[1], lw4[2], lw4[3]};

  float a0 = 0.f, a1 = 0.f, a2 = 0.f, a3 = 0.f;
  for (int n = 0; n < NVIEW; n++) {
    const float* Mx = sl2i + n * 16;
    float cam0 = Mx[0] * X + Mx[1] * Y + Mx[2]  * Zc + Mx[3];
    float cam1 = Mx[4] * X + Mx[5] * Y + Mx[6]  * Zc + Mx[7];
    float cam2 = Mx[8] * X + Mx[9] * Y + Mx[10] * Zc + Mx[11];
    float denom = fmaxf(cam2, 1e-5f);
    float u = cam0 / denom * (1.f / 704.f);
    float v = cam1 / denom * (1.f / 256.f);
    bool valid = (cam2 > 1e-5f) & (u > 0.f) & (u < 1.f) & (v > 0.f) & (v < 1.f);
    if (!valid) continue;
    float px3 = u * 22.f - 0.5f, py3 = v * 8.f - 0.5f;
    bool interior = (px3 >= 0.f) & (py3 >= 0.f) & (px3 < 21.f) & (py3 < 7.f);
    if (interior) {
      #pragma unroll
      for (int l = 0; l < 4; l++) {
        const int Hl = 64 >> l, Wl = 176 >> l;
        float pxl = u * (float)Wl - 0.5f;
        float pyl = v * (float)Hl - 0.5f;
        float fx = floorf(pxl), fy = floorf(pyl);
        int x0 = (int)fx, y0 = (int)fy;
        float wx = pxl - fx, wy = pyl - fy;
        float w1r = wy * swl[l], w0r = swl[l] - w1r;
        float w01 = w0r * wx, w00 = w0r - w01;
        float w11 = w1r * wx, w10 = w1r - w11;
        const _Float16* cp = FL[l]
            + ((size_t)n * (Hl * Wl) + (size_t)(y0 * Wl + x0)) * CN + c0;
        h4 v00 = *(const h4*)(cp);
        h4 v01 = *(const h4*)(cp + CN);
        h4 v10 = *(const h4*)(cp + Wl * CN);
        h4 v11 = *(const h4*)(cp + Wl * CN + CN);
        a0 = fmaf(w00, (float)v00[0], fmaf(w01, (float)v01[0], fmaf(w10, (float)v10[0], fmaf(w11, (float)v11[0], a0))));
        a1 = fmaf(w00, (float)v00[1], fmaf(w01, (float)v01[1], fmaf(w10, (float)v10[1], fmaf(w11, (float)v11[1], a1))));
        a2 = fmaf(w00, (float)v00[2], fmaf(w01, (float)v01[2], fmaf(w10, (float)v10[2], fmaf(w11, (float)v11[2], a2))));
        a3 = fmaf(w00, (float)v00[3], fmaf(w01, (float)v01[3], fmaf(w10, (float)v10[3], fmaf(w11, (float)v11[3], a3))));
      }
    } else {
      #pragma unroll
      for (int l = 0; l < 4; l++) {
        const int Hl = 64 >> l, Wl = 176 >> l;
        float pxl = u * (float)Wl - 0.5f;
        float pyl = v * (float)Hl - 0.5f;
        float fx = floorf(pxl), fy = floorf(pyl);
        int x0 = (int)fx, y0 = (int)fy;
        float wx = pxl - fx, wy = pyl - fy;
        float w1r = wy * swl[l], w0r = swl[l] - w1r;
        const float wxs[2] = {1.f - wx, wx};
        const float wrs[2] = {w0r, w1r};
        const _Float16* fb = FL[l] + (size_t)n * (Hl * Wl) * CN;
        #pragma unroll
        for (int cy = 0; cy < 2; cy++) {
          #pragma unroll
          for (int cx = 0; cx < 2; cx++) {
            int xi = x0 + cx, yi = y0 + cy;
            bool inb = ((unsigned)xi < (unsigned)Wl) & ((unsigned)yi < (unsigned)Hl);
            int off = inb ? (yi * Wl + xi) * CN : 0;
            float wgt = inb ? (wrs[cy] * wxs[cx]) : 0.f;
            h4 vv = *(const h4*)(fb + off + c0);
            a0 = fmaf(wgt, (float)vv[0], a0);
            a1 = fmaf(wgt, (float)vv[1], a1);
            a2 = fmaf(wgt, (float)vv[2], a2);
            a3 = fmaf(wgt, (float)vv[3], a3);
          }
        }
      }
    }
  }
  h4 o;
  o[0] = (_Float16)(a0 + pe0);
  o[1] = (_Float16)(a1 + pe1);
  o[2] = (_Float16)(a2 + pe2);
  o[3] = (_Float16)(a3 + pe3);
  *(h4*)&X0[(size_t)p * CN + c0] = o;
}

extern "C" void kernel_launch(void* const* d_in, const int* in_sizes, int n_in,
                              void* d_out, int out_size, void* d_ws, size_t ws_size,
                              hipStream_t stream) {
  const float* feat0 = (const float*)d_in[0];
  const float* feat1 = (const float*)d_in[1];
  const float* feat2 = (const float*)d_in[2];
  const float* feat3 = (const float*)d_in[3];
  const float* rp    = (const float*)d_in[4];
  const float* l2i   = (const float*)d_in[5];
  const float* pe_w1 = (const float*)d_in[6];
  const float* pe_b1 = (const float*)d_in[7];
  const float* pe_w2 = (const float*)d_in[8];
  const float* pe_b2 = (const float*)d_in[9];
  const float* wt_w  = (const float*)d_in[10];
  const float* wt_b  = (const float*)d_in[11];
  const float* hm_w1 = (const float*)d_in[12];
  const float* hm_b1 = (const float*)d_in[13];
  const float* hm_w2 = (const float*)d_in[14];
  const float* hm_b2 = (const float*)d_in[15];
  const float* hm_w3 = (const float*)d_in[16];
  const float* hm_b3 = (const float*)d_in[17];
  const float* hm_w4 = (const float*)d_in[18];
  const float* hm_b4 = (const float*)d_in[19];
  float* out = (float*)d_out;

  char* ws = (char*)d_ws;
  typedef _Float16 h16;
  h16* wPE1 = (h16*)(ws + 0);         // 256x64
  h16* wPE2 = (h16*)(ws + 65536);     // 128x256
  h16* wH1  = (h16*)(ws + 196608);    // 1024x512
  h16* wH2  = (h16*)(ws + 2293760);   // 1024x1024
  h16* wH3  = (h16*)(ws + 6488064);   // 1024x1024
  h16* wH4  = (h16*)(ws + 10682368);  // 128x1024

  h16*   posE = (h16*)(ws + 11534336);   // [80000][128] f16
  float* lwga = (float*)(ws + 33000000); // [80000][4] f32 level weights
  h16*   hpe  = (h16*)(ws + 53000192);   // [80000][256] f16
  h16*   pein = (h16*)(ws + 94000128);   // [80000][64] f16
  h16*   X0   = (h16*)(ws + 53000192);   // [20000][512] f16 (hpe dead)
  h16*   H1   = (h16*)(ws + 94000128);   // [20000][1024] f16 (pein dead)
  h16*   H2   = (h16*)(ws + 11534336);   // (posE dead after sample)
  h16*   H3   = (h16*)(ws + 94000128);   // (H1 dead)
  h16*   f16b = (h16*)(ws + 136000000);  // feats f16, 22.98 MB

  // 0. single prep dispatch
  prep_all<<<33956, 256, 0, stream>>>(pe_w1, pe_w2, hm_w1, hm_w2, hm_w3, hm_w4,
                                      (h16*)ws, feat0, feat1, feat2, feat3,
                                      f16b, rp, pein);

  // 1. PE MLP: 64 -> 256 (relu) -> 128 (f16 posE)
  gemm_h<true, 1><<<2 * 625, 256, 0, stream>>>(pein, wPE1, pe_b1, nullptr, hpe, PN, 256, 64, 2);
  gemm_h<false, 1><<<1 * 625, 256, 0, stream>>>(hpe, wPE2, pe_b2, nullptr, posE, PN, 128, 256, 1);

  // 2. level-weight softmax
  lw_kernel<<<PN / 16, 256, 0, stream>>>(posE, wt_w, wt_b, lwga);

  // 3. fused projection + sampling -> X0 f16
  sample_kernel<<<PN / 8, 256, 0, stream>>>(f16b, rp, l2i, lwga, posE, X0);

  // 4. head MLP: H1-H3 on the m97 BK=64 single-buffer structure; H4 on gemm_h
  gemm97<true, 1><<<8 * 157, 256, 0, stream>>>(X0, wH1, hm_b1, nullptr, H1, QN, 1024, 512, 8);
  gemm97<true, 1><<<8 * 157, 256, 0, stream>>>(H1, wH2, hm_b2, nullptr, H2, QN, 1024, 1024, 8);
  gemm97<true, 1><<<8 * 157, 256, 0, stream>>>(H2, wH3, hm_b3, nullptr, H3, QN, 1024, 1024, 8);
  gemm_h<false, 0><<<1 * 157, 256, 0, stream>>>(H3, wH4, hm_b4, out, nullptr, QN, 128, 1024, 1);
}

// Round 21
// 304.640 us; speedup vs baseline: 1.3062x; 1.0048x over previous
//
#include <hip/hip_runtime.h>
#include <math.h>

#define QN 20000
#define PN 80000   // QN*4
#define CN 128
#define NVIEW 6

typedef __attribute__((ext_vector_type(8))) _Float16 h8;
typedef __attribute__((ext_vector_type(4))) _Float16 h4;
typedef __attribute__((ext_vector_type(4))) float f32x4;

__device__ __forceinline__ void gload16(const void* g, void* l) {
  __builtin_amdgcn_global_load_lds(
      (const __attribute__((address_space(1))) void*)g,
      (__attribute__((address_space(3))) void*)l, 16, 0, 0);
}

// ---------------- prep mega-dispatch: wtrans(6 layers) + fcvt + pe_in --------
__global__ __launch_bounds__(256) void prep_all(
    const float* __restrict__ w0, const float* __restrict__ w1,
    const float* __restrict__ w2, const float* __restrict__ w3,
    const float* __restrict__ w4, const float* __restrict__ w5,
    _Float16* __restrict__ wbase,
    const float* __restrict__ s0, const float* __restrict__ s1,
    const float* __restrict__ s2, const float* __restrict__ s3,
    _Float16* __restrict__ fdst,
    const float* __restrict__ rp, _Float16* __restrict__ pedst) {
  int b = blockIdx.x;
  if (b < 2736) {  // ---- weight transpose ----
    __shared__ float t[32][33];
    const float* W; _Float16* T; int K, N, Kp, nbx, lb;
    if (b < 16)        { W = w0; T = wbase + 0;       K = 60;   N = 256;  Kp = 64;   nbx = 8;  lb = b; }
    else if (b < 48)   { W = w1; T = wbase + 32768;   K = 256;  N = 128;  Kp = 256;  nbx = 4;  lb = b - 16; }
    else if (b < 560)  { W = w2; T = wbase + 98304;   K = 512;  N = 1024; Kp = 512;  nbx = 32; lb = b - 48; }
    else if (b < 1584) { W = w3; T = wbase + 1146880; K = 1024; N = 1024; Kp = 1024; nbx = 32; lb = b - 560; }
    else if (b < 2608) { W = w4; T = wbase + 3244032; K = 1024; N = 1024; Kp = 1024; nbx = 32; lb = b - 1584; }
    else               { W = w5; T = wbase + 5341184; K = 1024; N = 128;  Kp = 1024; nbx = 4;  lb = b - 2608; }
    const int n0 = (lb % nbx) * 32, k0 = (lb / nbx) * 32;
    const int tx = threadIdx.x & 31, ty = threadIdx.x >> 5;
    #pragma unroll
    for (int j = 0; j < 4; ++j) {
      int k = k0 + ty + j * 8;
      t[ty + j * 8][tx] = (k < K) ? W[(size_t)k * N + n0 + tx] : 0.f;
    }
    __syncthreads();
    #pragma unroll
    for (int j = 0; j < 4; ++j) {
      int n = n0 + ty + j * 8;
      int k = k0 + tx;
      T[(size_t)n * Kp + k] = (_Float16)t[tx][ty + j * 8];
    }
  } else if (b < 13956) {  // ---- feats f32 -> f16 ----
    size_t i = (size_t)(b - 2736) * 256 + threadIdx.x;  // float4 index
    const float* s; size_t off;
    if (i < 2162688)      { s = s0; off = 0; }
    else if (i < 2703360) { s = s1; off = 2162688; }
    else if (i < 2838528) { s = s2; off = 2703360; }
    else                  { s = s3; off = 2838528; }
    f32x4 v = *(const f32x4*)(s + (i - off) * 4);
    h4 o;
    o[0] = (_Float16)v[0]; o[1] = (_Float16)v[1];
    o[2] = (_Float16)v[2]; o[3] = (_Float16)v[3];
    *(h4*)(fdst + i * 4) = o;
  } else {  // ---- PE features ----
    int idx = (b - 13956) * 256 + threadIdx.x;
    int p = idx >> 6, k = idx & 63;
    float val = 0.f;
    if (k < 60) {
      int q = p >> 2, z = p & 3;
      int d = k / 20, r = k - d * 20;
      int j = (r >= 10) ? (r - 10) : r;
      float pos = rp[((size_t)z * QN + q) * 3 + d];
      float ang = pos * ((float)(1 << j) * 3.14159265358979323846f);
      val = (r >= 10) ? cosf(ang) : sinf(ang);
    }
    pedst[idx] = (_Float16)val;
  }
}

// ---------------- level-weight softmax: lw[p][4] = softmax(posE@wtw + wtb) ---
__global__ __launch_bounds__(256) void lw_kernel(const _Float16* __restrict__ posE,
                                                 const float* __restrict__ wtw,
                                                 const float* __restrict__ wtb,
                                                 float* __restrict__ lw) {
  __shared__ float swtT[512];  // transposed [4][128]
  __shared__ float sb[4];
  const int tid = threadIdx.x;
  for (int i = tid; i < 512; i += 256) swtT[(i & 3) * 128 + (i >> 2)] = wtw[i];
  if (tid < 4) sb[tid] = wtb[tid];
  __syncthreads();

  const int wave = tid >> 6, lane = tid & 63;
  const int grp = lane >> 4, s = lane & 15;
  const int p = blockIdx.x * 16 + wave * 4 + grp;
  const int c0 = s * 8;
  h8 pa = *(const h8*)(posE + (size_t)p * CN + c0);

  float lg[4];
  #pragma unroll
  for (int l = 0; l < 4; ++l) {
    const float* w = swtT + l * 128 + c0;
    float acc = 0.f;
    #pragma unroll
    for (int j = 0; j < 8; ++j) acc = fmaf((float)pa[j], w[j], acc);
    lg[l] = acc;
  }
  #pragma unroll
  for (int off = 8; off > 0; off >>= 1) {
    lg[0] += __shfl_xor(lg[0], off);
    lg[1] += __shfl_xor(lg[1], off);
    lg[2] += __shfl_xor(lg[2], off);
    lg[3] += __shfl_xor(lg[3], off);
  }
  lg[0] += sb[0]; lg[1] += sb[1]; lg[2] += sb[2]; lg[3] += sb[3];
  float mx = fmaxf(fmaxf(lg[0], lg[1]), fmaxf(lg[2], lg[3]));
  float e0 = __expf(lg[0] - mx), e1 = __expf(lg[1] - mx);
  float e2 = __expf(lg[2] - mx), e3 = __expf(lg[3] - mx);
  float esr = 1.f / (e0 + e1 + e2 + e3);
  if (s == 0) {
    f32x4 o = {e0 * esr, e1 * esr, e2 * esr, e3 * esr};
    *(f32x4*)(lw + (size_t)p * 4) = o;
  }
}

// ---------------- m97-structure GEMM: 128x128, BK=64, SINGLE-buffered --------
// r20-verified: beat the BK=32 dbuf config (H-layers 66.9 -> <60us). Per tile:
// STAGE -> __syncthreads -> 32 MFMA/wave -> __syncthreads. Half the drains
// per unit K; TLP (32KB LDS -> 4 blocks/CU) hides staging (m114). Swizzle
// slot ^= row&7 involution on source & read. K % 64 == 0, N % 128 == 0.
template <bool RELU, int OUT>
__global__ __launch_bounds__(256, 4) void gemm97(const _Float16* __restrict__ A,
                                                 const _Float16* __restrict__ B,
                                                 const float* __restrict__ bias,
                                                 float* __restrict__ Cf,
                                                 _Float16* __restrict__ Ch,
                                                 int M, int N, int K,
                                                 int nbn) {
  __shared__ _Float16 smA[128 * 64];  // 16 KB
  __shared__ _Float16 smB[128 * 64];  // 16 KB
  const int tid = threadIdx.x;
  const int wave = tid >> 6, lane = tid & 63;
  const int wr = wave >> 1, wc = wave & 1;
  const int g = lane >> 4, r16 = lane & 15;

  const int nwg = gridDim.x;
  const int q8 = nwg >> 3, r8 = nwg & 7;
  const int xcd = blockIdx.x & 7, sub = blockIdx.x >> 3;
  const int wg = (xcd < r8 ? xcd * (q8 + 1) : r8 * (q8 + 1) + (xcd - r8) * q8) + sub;
  const int bn = (wg % nbn) * 128;
  const int bm = (wg / nbn) * 128;
  const int nt = K >> 6;  // K/64 tiles

  f32x4 acc[4][4];
  #pragma unroll
  for (int i = 0; i < 4; ++i)
    #pragma unroll
    for (int j = 0; j < 4; ++j) acc[i][j] = {0.f, 0.f, 0.f, 0.f};

  auto STAGE = [&](int t) {
    const int kof = t << 6;
    const int rsub = lane >> 3;                    // 0..7 row within group
    const int slot0 = lane & 7;                    // 16B slot within row
    #pragma unroll
    for (int pl = 0; pl < 2; ++pl) {
      const _Float16* P = (pl == 0) ? A : B;
      _Float16* S = (pl == 0) ? smA : smB;
      const int rbase = (pl == 0) ? bm : bn;
      #pragma unroll
      for (int i = 0; i < 4; ++i) {
        int group = wave * 4 + i;                  // 0..15 (8 rows each)
        int row = group * 8 + rsub;                // 0..127
        int slot = slot0 ^ (row & 7);              // pre-swizzled source
        int gr = rbase + row;
        if (pl == 0 && gr >= M) gr = M - 1;
        gload16(P + (size_t)gr * K + kof + slot * 8,
                &S[group * 512]);                  // linear LDS dest
      }
    }
  };

  auto COMPUTE = [&]() {
    #pragma unroll
    for (int kk = 0; kk < 2; ++kk) {
      h8 a[4], b[4];
      #pragma unroll
      for (int mi = 0; mi < 4; ++mi) {
        int row = wr * 64 + mi * 16 + r16;
        int off = row * 64 + (((kk * 4 + g) ^ (row & 7)) * 8);  // swizzled
        a[mi] = *(const h8*)&smA[off];
      }
      #pragma unroll
      for (int ni = 0; ni < 4; ++ni) {
        int row = wc * 64 + ni * 16 + r16;
        int off = row * 64 + (((kk * 4 + g) ^ (row & 7)) * 8);
        b[ni] = *(const h8*)&smB[off];
      }
      #pragma unroll
      for (int mi = 0; mi < 4; ++mi)
        #pragma unroll
        for (int ni = 0; ni < 4; ++ni)
          acc[mi][ni] = __builtin_amdgcn_mfma_f32_16x16x32_f16(a[mi], b[ni], acc[mi][ni], 0, 0, 0);
    }
  };

  for (int t = 0; t < nt; ++t) {
    STAGE(t);
    __syncthreads();   // drain: tile t landed
    COMPUTE();
    __syncthreads();   // WAR: all reads done before next STAGE overwrites
  }

  #pragma unroll
  for (int mi = 0; mi < 4; ++mi) {
    int gr0 = bm + wr * 64 + mi * 16 + (lane >> 4) * 4;
    #pragma unroll
    for (int ni = 0; ni < 4; ++ni) {
      int gc = bn + wc * 64 + ni * 16 + r16;
      float bv = bias[gc];
      #pragma unroll
      for (int r = 0; r < 4; ++r) {
        int row = gr0 + r;
        if (row >= M) continue;
        float v = acc[mi][ni][r] + bv;
        if (RELU) v = fmaxf(v, 0.f);
        if (OUT == 0) Cf[(size_t)row * N + gc] = v;
        else          Ch[(size_t)row * N + gc] = (_Float16)v;
      }
    }
  }
}

// ---------------- fused projection + bilinear sample -------------------------
// 2 pts/wave + interior fast path + f16 feats + precomputed lw (r18/r20: 66.9us)
__global__ __launch_bounds__(256) void sample_kernel(
    const _Float16* __restrict__ fbase,
    const float* __restrict__ rp, const float* __restrict__ l2i,
    const float* __restrict__ lw,
    const _Float16* __restrict__ posE, _Float16* __restrict__ X0) {
  __shared__ float sl2i[96];
  const int tid = threadIdx.x;
  if (tid < 96) sl2i[tid] = l2i[tid];
  __syncthreads();

  const _Float16* FL[4] = {fbase, fbase + 8650752, fbase + 10813440,
                           fbase + 11354112};

  const int wave = tid >> 6, lane = tid & 63;
  const int half = lane >> 5, s = lane & 31;
  const int p = blockIdx.x * 8 + wave * 2 + half;
  const int q = p >> 2, z = p & 3;

  const float X  = rp[((size_t)z * QN + q) * 3 + 0] * 100.f - 50.f;
  const float Y  = rp[((size_t)z * QN + q) * 3 + 1] * 100.f - 50.f;
  const float Zc = rp[((size_t)z * QN + q) * 3 + 2] * 8.f - 4.f;

  const int c0 = s * 4;
  h4 pa = *(const h4*)(posE + (size_t)p * CN + c0);
  const float pe0 = (float)pa[0], pe1 = (float)pa[1];
  const float pe2 = (float)pa[2], pe3 = (float)pa[3];

  f32x4 lw4 = *(const f32x4*)(lw + (size_t)p * 4);
  float swl[4] = {lw4[0], lw4[1], lw4[2], lw4[3]};

  float a0 = 0.f, a1 = 0.f, a2 = 0.f, a3 = 0.f;
  for (int n = 0; n < NVIEW; n++) {
    const float* Mx = sl2i + n * 16;
    float cam0 = Mx[0] * X + Mx[1] * Y + Mx[2]  * Zc + Mx[3];
    float cam1 = Mx[4] * X + Mx[5] * Y + Mx[6]  * Zc + Mx[7];
    float cam2 = Mx[8] * X + Mx[9] * Y + Mx[10] * Zc + Mx[11];
    float denom = fmaxf(cam2, 1e-5f);
    float u = cam0 / denom * (1.f / 704.f);
    float v = cam1 / denom * (1.f / 256.f);
    bool valid = (cam2 > 1e-5f) & (u > 0.f) & (u < 1.f) & (v > 0.f) & (v < 1.f);
    if (!valid) continue;
    float px3 = u * 22.f - 0.5f, py3 = v * 8.f - 0.5f;
    bool interior = (px3 >= 0.f) & (py3 >= 0.f) & (px3 < 21.f) & (py3 < 7.f);
    if (interior) {
      #pragma unroll
      for (int l = 0; l < 4; l++) {
        const int Hl = 64 >> l, Wl = 176 >> l;
        float pxl = u * (float)Wl - 0.5f;
        float pyl = v * (float)Hl - 0.5f;
        float fx = floorf(pxl), fy = floorf(pyl);
        int x0 = (int)fx, y0 = (int)fy;
        float wx = pxl - fx, wy = pyl - fy;
        float w1r = wy * swl[l], w0r = swl[l] - w1r;
        float w01 = w0r * wx, w00 = w0r - w01;
        float w11 = w1r * wx, w10 = w1r - w11;
        const _Float16* cp = FL[l]
            + ((size_t)n * (Hl * Wl) + (size_t)(y0 * Wl + x0)) * CN + c0;
        h4 v00 = *(const h4*)(cp);
        h4 v01 = *(const h4*)(cp + CN);
        h4 v10 = *(const h4*)(cp + Wl * CN);
        h4 v11 = *(const h4*)(cp + Wl * CN + CN);
        a0 = fmaf(w00, (float)v00[0], fmaf(w01, (float)v01[0], fmaf(w10, (float)v10[0], fmaf(w11, (float)v11[0], a0))));
        a1 = fmaf(w00, (float)v00[1], fmaf(w01, (float)v01[1], fmaf(w10, (float)v10[1], fmaf(w11, (float)v11[1], a1))));
        a2 = fmaf(w00, (float)v00[2], fmaf(w01, (float)v01[2], fmaf(w10, (float)v10[2], fmaf(w11, (float)v11[2], a2))));
        a3 = fmaf(w00, (float)v00[3], fmaf(w01, (float)v01[3], fmaf(w10, (float)v10[3], fmaf(w11, (float)v11[3], a3))));
      }
    } else {
      #pragma unroll
      for (int l = 0; l < 4; l++) {
        const int Hl = 64 >> l, Wl = 176 >> l;
        float pxl = u * (float)Wl - 0.5f;
        float pyl = v * (float)Hl - 0.5f;
        float fx = floorf(pxl), fy = floorf(pyl);
        int x0 = (int)fx, y0 = (int)fy;
        float wx = pxl - fx, wy = pyl - fy;
        float w1r = wy * swl[l], w0r = swl[l] - w1r;
        const float wxs[2] = {1.f - wx, wx};
        const float wrs[2] = {w0r, w1r};
        const _Float16* fb = FL[l] + (size_t)n * (Hl * Wl) * CN;
        #pragma unroll
        for (int cy = 0; cy < 2; cy++) {
          #pragma unroll
          for (int cx = 0; cx < 2; cx++) {
            int xi = x0 + cx, yi = y0 + cy;
            bool inb = ((unsigned)xi < (unsigned)Wl) & ((unsigned)yi < (unsigned)Hl);
            int off = inb ? (yi * Wl + xi) * CN : 0;
            float wgt = inb ? (wrs[cy] * wxs[cx]) : 0.f;
            h4 vv = *(const h4*)(fb + off + c0);
            a0 = fmaf(wgt, (float)vv[0], a0);
            a1 = fmaf(wgt, (float)vv[1], a1);
            a2 = fmaf(wgt, (float)vv[2], a2);
            a3 = fmaf(wgt, (float)vv[3], a3);
          }
        }
      }
    }
  }
  h4 o;
  o[0] = (_Float16)(a0 + pe0);
  o[1] = (_Float16)(a1 + pe1);
  o[2] = (_Float16)(a2 + pe2);
  o[3] = (_Float16)(a3 + pe3);
  *(h4*)&X0[(size_t)p * CN + c0] = o;
}

extern "C" void kernel_launch(void* const* d_in, const int* in_sizes, int n_in,
                              void* d_out, int out_size, void* d_ws, size_t ws_size,
                              hipStream_t stream) {
  const float* feat0 = (const float*)d_in[0];
  const float* feat1 = (const float*)d_in[1];
  const float* feat2 = (const float*)d_in[2];
  const float* feat3 = (const float*)d_in[3];
  const float* rp    = (const float*)d_in[4];
  const float* l2i   = (const float*)d_in[5];
  const float* pe_w1 = (const float*)d_in[6];
  const float* pe_b1 = (const float*)d_in[7];
  const float* pe_w2 = (const float*)d_in[8];
  const float* pe_b2 = (const float*)d_in[9];
  const float* wt_w  = (const float*)d_in[10];
  const float* wt_b  = (const float*)d_in[11];
  const float* hm_w1 = (const float*)d_in[12];
  const float* hm_b1 = (const float*)d_in[13];
  const float* hm_w2 = (const float*)d_in[14];
  const float* hm_b2 = (const float*)d_in[15];
  const float* hm_w3 = (const float*)d_in[16];
  const float* hm_b3 = (const float*)d_in[17];
  const float* hm_w4 = (const float*)d_in[18];
  const float* hm_b4 = (const float*)d_in[19];
  float* out = (float*)d_out;

  char* ws = (char*)d_ws;
  typedef _Float16 h16;
  h16* wPE1 = (h16*)(ws + 0);         // 256x64
  h16* wPE2 = (h16*)(ws + 65536);     // 128x256
  h16* wH1  = (h16*)(ws + 196608);    // 1024x512
  h16* wH2  = (h16*)(ws + 2293760);   // 1024x1024
  h16* wH3  = (h16*)(ws + 6488064);   // 1024x1024
  h16* wH4  = (h16*)(ws + 10682368);  // 128x1024

  h16*   posE = (h16*)(ws + 11534336);   // [80000][128] f16
  float* lwga = (float*)(ws + 33000000); // [80000][4] f32 level weights
  h16*   hpe  = (h16*)(ws + 53000192);   // [80000][256] f16
  h16*   pein = (h16*)(ws + 94000128);   // [80000][64] f16
  h16*   X0   = (h16*)(ws + 53000192);   // [20000][512] f16 (hpe dead)
  h16*   H1   = (h16*)(ws + 94000128);   // [20000][1024] f16 (pein dead)
  h16*   H2   = (h16*)(ws + 11534336);   // (posE dead after sample)
  h16*   H3   = (h16*)(ws + 94000128);   // (H1 dead)
  h16*   f16b = (h16*)(ws + 136000000);  // feats f16, 22.98 MB

  // 0. single prep dispatch
  prep_all<<<33956, 256, 0, stream>>>(pe_w1, pe_w2, hm_w1, hm_w2, hm_w3, hm_w4,
                                      (h16*)ws, feat0, feat1, feat2, feat3,
                                      f16b, rp, pein);

  // 1. PE MLP: 64 -> 256 (relu) -> 128 (f16 posE), all on gemm97
  gemm97<true, 1><<<2 * 625, 256, 0, stream>>>(pein, wPE1, pe_b1, nullptr, hpe, PN, 256, 64, 2);
  gemm97<false, 1><<<1 * 625, 256, 0, stream>>>(hpe, wPE2, pe_b2, nullptr, posE, PN, 128, 256, 1);

  // 2. level-weight softmax
  lw_kernel<<<PN / 16, 256, 0, stream>>>(posE, wt_w, wt_b, lwga);

  // 3. fused projection + sampling -> X0 f16
  sample_kernel<<<PN / 8, 256, 0, stream>>>(f16b, rp, l2i, lwga, posE, X0);

  // 4. head MLP: all layers on the m97 BK=64 single-buffer structure
  gemm97<true, 1><<<8 * 157, 256, 0, stream>>>(X0, wH1, hm_b1, nullptr, H1, QN, 1024, 512, 8);
  gemm97<true, 1><<<8 * 157, 256, 0, stream>>>(H1, wH2, hm_b2, nullptr, H2, QN, 1024, 1024, 8);
  gemm97<true, 1><<<8 * 157, 256, 0, stream>>>(H2, wH3, hm_b3, nullptr, H3, QN, 1024, 1024, 8);
  gemm97<false, 0><<<1 * 157, 256, 0, stream>>>(H3, wH4, hm_b4, out, nullptr, QN, 128, 1024, 1);
}